// Round 1
// baseline (9780.405 us; speedup 1.0000x reference)
//
#include <hip/hip_runtime.h>
#include <math.h>

#define BB 4
#define LL 2048
#define DM 512
#define NH 8
#define DK 64
#define RANK 20
#define QT 8

// ---------------- build dense W from TT cores ----------------
// W[i][j] = sum_{u,v,r} g1[0,w,o,u] g2[u,x,p,v] g3[v,y,q,r] g4[r,z,s,0]
// i = ((w*4+x)*8+y)*4+z ; j = ((o*4+p)*8+q)*4+s
__global__ __launch_bounds__(256) void build_w_kernel(
    const float* __restrict__ g1, const float* __restrict__ g2,
    const float* __restrict__ g3, const float* __restrict__ g4,
    float* __restrict__ W)
{
    int idx = blockIdx.x * 256 + threadIdx.x;       // 16384 threads: (w,x,y,o,p,q)
    if (idx >= 4*4*8*4*4*8) return;
    int q = idx & 7; int t = idx >> 3;
    int p = t & 3;  t >>= 2;
    int o = t & 3;  t >>= 2;
    int y = t & 7;  t >>= 3;
    int x = t & 3;  t >>= 2;
    int w = t & 3;

    float c[RANK];
    for (int v = 0; v < RANK; ++v) c[v] = 0.f;
    for (int u = 0; u < RANK; ++u) {
        float a = g1[(w*4 + o)*RANK + u];
        const float* g2p = g2 + ((u*4 + x)*4 + p)*RANK;
        for (int v = 0; v < RANK; ++v) c[v] += a * g2p[v];
    }
    float d[RANK];
    for (int r = 0; r < RANK; ++r) d[r] = 0.f;
    for (int v = 0; v < RANK; ++v) {
        float cv = c[v];
        const float* g3p = g3 + ((v*8 + y)*8 + q)*RANK;
        for (int r = 0; r < RANK; ++r) d[r] += cv * g3p[r];
    }
    for (int z = 0; z < 4; ++z) {
        for (int s = 0; s < 4; ++s) {
            float acc = 0.f;
            for (int r = 0; r < RANK; ++r) acc += d[r] * g4[(r*4 + z)*4 + s];
            int i = ((w*4 + x)*8 + y)*4 + z;
            int j = ((o*4 + p)*8 + q)*4 + s;
            W[i*DM + j] = acc;
        }
    }
}

// ---------------- tiled fp32 GEMM: [8192,512] x [512,512] + bias ----------------
// mode 0: out[((b*NH+h)*LL + l)*DK + d]   (projection, head-transposed)
// mode 1: out[m*DM + n]                   (fc, row-major)
__global__ __launch_bounds__(256) void gemm_kernel(
    const float* __restrict__ X, const float* __restrict__ W,
    const float* __restrict__ bias, float* __restrict__ out, int mode)
{
    __shared__ float As[16][65];   // [k][m]
    __shared__ float Bs[16][65];   // [k][n]
    int m0 = blockIdx.x * 64;
    int n0 = blockIdx.y * 64;
    int t  = threadIdx.x;
    int tx = t & 15, ty = t >> 4;
    float acc[4][4] = {};

    for (int k0 = 0; k0 < DM; k0 += 16) {
        for (int i = 0; i < 4; ++i) {
            int e = t + i*256;
            int m = e >> 4, k = e & 15;
            As[k][m] = X[(size_t)(m0+m)*DM + k0 + k];
        }
        for (int i = 0; i < 4; ++i) {
            int e = t + i*256;
            int k = e >> 6, n = e & 63;
            Bs[k][n] = W[(size_t)(k0+k)*DM + n0 + n];
        }
        __syncthreads();
        #pragma unroll
        for (int k = 0; k < 16; ++k) {
            float a[4], b[4];
            #pragma unroll
            for (int i = 0; i < 4; ++i) a[i] = As[k][ty*4+i];
            #pragma unroll
            for (int j = 0; j < 4; ++j) b[j] = Bs[k][tx*4+j];
            #pragma unroll
            for (int i = 0; i < 4; ++i)
                #pragma unroll
                for (int j = 0; j < 4; ++j) acc[i][j] += a[i]*b[j];
        }
        __syncthreads();
    }

    for (int i = 0; i < 4; ++i) {
        int m = m0 + ty*4 + i;
        int l = m & (LL-1), b = m >> 11;
        for (int j = 0; j < 4; ++j) {
            int n = n0 + tx*4 + j;
            float val = acc[i][j] + bias[n];
            if (mode == 0) {
                int h = n >> 6, d = n & 63;
                out[(((size_t)(b*NH + h))*LL + l)*DK + d] = val;
            } else {
                out[(size_t)m*DM + n] = val;
            }
        }
    }
}

// ---------------- attention: scores + softmax + attn-write + PV ----------------
// one block per (b, h, 8 q-rows); 256 threads
__global__ __launch_bounds__(256) void attn_kernel(
    const float* __restrict__ Qh, const float* __restrict__ Kh,
    const float* __restrict__ Vh, float* __restrict__ attn,
    float* __restrict__ O)
{
    __shared__ float Ss[QT][LL];        // 64 KB
    __shared__ float Kc[128][DK+1];     // 33.3 KB (padded: conflict-free)
    __shared__ float Qs[QT][DK];        // 2 KB

    int blk = blockIdx.x;
    int qt  = blk % (LL/QT);
    int bh  = blk / (LL/QT);            // b*NH + h
    int q0  = qt * QT;
    const float* Qp = Qh + (size_t)bh * LL * DK;
    const float* Kp = Kh + (size_t)bh * LL * DK;
    const float* Vp = Vh + (size_t)bh * LL * DK;
    int t = threadIdx.x;

    for (int e = t; e < QT*DK; e += 256)
        Qs[e/DK][e%DK] = Qp[(size_t)(q0 + e/DK)*DK + (e%DK)];
    __syncthreads();

    // ---- scores in chunks of 128 K-rows ----
    int lc    = t & 127;
    int rbase = (t >> 7) * 4;           // 0 or 4
    for (int kc = 0; kc < LL; kc += 128) {
        for (int e = t; e < 128*DK; e += 256) {
            int r = e >> 6, c2 = e & 63;
            Kc[r][c2] = Kp[(size_t)(kc + r)*DK + c2];
        }
        __syncthreads();
        float acc[4] = {0.f, 0.f, 0.f, 0.f};
        #pragma unroll 8
        for (int d = 0; d < DK; ++d) {
            float kv = Kc[lc][d];
            #pragma unroll
            for (int r = 0; r < 4; ++r) acc[r] += Qs[rbase+r][d] * kv;
        }
        #pragma unroll
        for (int r = 0; r < 4; ++r) Ss[rbase+r][kc + lc] = acc[r] * 0.125f;
        __syncthreads();
    }

    // ---- softmax: 8 rows x 32 threads ----
    {
        int g  = t >> 5;                // row 0..7
        int lg = t & 31;
        float m = -1e30f;
        for (int c = lg; c < LL; c += 32) m = fmaxf(m, Ss[g][c]);
        #pragma unroll
        for (int off = 16; off >= 1; off >>= 1) m = fmaxf(m, __shfl_xor(m, off));
        float sum = 0.f;
        for (int c = lg; c < LL; c += 32) {
            float e = __expf(Ss[g][c] - m);
            Ss[g][c] = e;
            sum += e;
        }
        #pragma unroll
        for (int off = 16; off >= 1; off >>= 1) sum += __shfl_xor(sum, off);
        float inv = 1.0f / sum;
        for (int c = lg; c < LL; c += 32) Ss[g][c] *= inv;
    }
    __syncthreads();

    // ---- write attn (second output region) ----
    float* ap = attn + ((size_t)bh * LL + q0) * LL;
    for (int r = 0; r < QT; ++r)
        for (int c = t; c < LL; c += 256)
            ap[(size_t)r*LL + c] = Ss[r][c];

    // ---- PV: O[r][d] = sum_c P[r][c] * V[c][d] ----
    int d2 = t & 63;
    int rr = t >> 6;                    // 0..3
    int b  = bh >> 3, h = bh & 7;
    #pragma unroll
    for (int rh = 0; rh < 2; ++rh) {
        int r = rr + rh*4;
        float acc = 0.f;
        #pragma unroll 4
        for (int c = 0; c < LL; ++c) acc += Ss[r][c] * Vp[(size_t)c*DK + d2];
        O[((size_t)b*LL + q0 + r)*DM + h*DK + d2] = acc;
    }
}

// ---------------- residual + LayerNorm ----------------
__global__ __launch_bounds__(256) void ln_kernel(
    const float* __restrict__ Y, const float* __restrict__ Res,
    const float* __restrict__ g, const float* __restrict__ bta,
    float* __restrict__ out)
{
    int row = blockIdx.x;
    int t = threadIdx.x;
    const float* yp = Y  + (size_t)row*DM;
    const float* rp = Res + (size_t)row*DM;
    float v0 = yp[t]       + rp[t];
    float v1 = yp[t + 256] + rp[t + 256];
    float s1 = v0 + v1;
    float s2 = v0*v0 + v1*v1;
    __shared__ float red1[4], red2[4];
    #pragma unroll
    for (int off = 32; off >= 1; off >>= 1) {
        s1 += __shfl_xor(s1, off);
        s2 += __shfl_xor(s2, off);
    }
    int w = t >> 6;
    if ((t & 63) == 0) { red1[w] = s1; red2[w] = s2; }
    __syncthreads();
    float mu = (red1[0]+red1[1]+red1[2]+red1[3]) * (1.0f/DM);
    float ms = (red2[0]+red2[1]+red2[2]+red2[3]) * (1.0f/DM);
    float inv = rsqrtf(ms - mu*mu + 1e-12f);
    out[(size_t)row*DM + t]       = (v0 - mu)*inv*g[t]       + bta[t];
    out[(size_t)row*DM + t + 256] = (v1 - mu)*inv*g[t + 256] + bta[t + 256];
}

extern "C" void kernel_launch(void* const* d_in, const int* in_sizes, int n_in,
                              void* d_out, int out_size, void* d_ws, size_t ws_size,
                              hipStream_t stream)
{
    // input order: [wq_g1,wq_g2,wq_g3,wq_g4,wq_b, wk_*, wv_*, fc_*, q, k, v, ln_g, ln_b]
    const float* G[4][5];
    for (int s = 0; s < 4; ++s)
        for (int i = 0; i < 5; ++i)
            G[s][i] = (const float*)d_in[s*5 + i];
    const float* q   = (const float*)d_in[20];
    const float* k   = (const float*)d_in[21];
    const float* v   = (const float*)d_in[22];
    const float* lng = (const float*)d_in[23];
    const float* lnb = (const float*)d_in[24];

    float* out  = (float*)d_out;                         // [B,L,DM]
    float* attn = out + (size_t)BB*LL*DM;                // [B,NH,L,L]

    float* ws = (float*)d_ws;
    float* W  = ws;                                      // 4 * 512*512
    float* qh = W  + 4*(size_t)DM*DM;                    // [B,NH,L,DK]
    float* kh = qh + (size_t)BB*LL*DM;
    float* vh = kh + (size_t)BB*LL*DM;
    float* o  = vh + (size_t)BB*LL*DM;                   // [B,L,DM]
    float* y  = qh;                                      // reuse qh after attention

    for (int s = 0; s < 4; ++s)
        build_w_kernel<<<64, 256, 0, stream>>>(G[s][0], G[s][1], G[s][2], G[s][3],
                                               W + (size_t)s*DM*DM);

    dim3 gg(BB*LL/64, DM/64);
    gemm_kernel<<<gg, 256, 0, stream>>>(q, W + 0*(size_t)DM*DM, G[0][4], qh, 0);
    gemm_kernel<<<gg, 256, 0, stream>>>(k, W + 1*(size_t)DM*DM, G[1][4], kh, 0);
    gemm_kernel<<<gg, 256, 0, stream>>>(v, W + 2*(size_t)DM*DM, G[2][4], vh, 0);

    attn_kernel<<<BB*NH*(LL/QT), 256, 0, stream>>>(qh, kh, vh, attn, o);

    gemm_kernel<<<gg, 256, 0, stream>>>(o, W + 3*(size_t)DM*DM, G[3][4], y, 1);

    ln_kernel<<<BB*LL, 256, 0, stream>>>(y, q, lng, lnb, out);
}

// Round 2
// 738.398 us; speedup vs baseline: 13.2454x; 13.2454x over previous
//
#include <hip/hip_runtime.h>
#include <hip/hip_bf16.h>
#include <math.h>

#define BB 4
#define LL 2048
#define DM 512
#define NH 8
#define DK 64
#define RANK 20

typedef __attribute__((ext_vector_type(8))) short short8;
typedef __attribute__((ext_vector_type(4))) float f32x4;
typedef __hip_bfloat16 bf16;

// ---------------- build dense W from TT cores ----------------
__global__ __launch_bounds__(256) void build_w_kernel(
    const float* __restrict__ g1, const float* __restrict__ g2,
    const float* __restrict__ g3, const float* __restrict__ g4,
    float* __restrict__ W)
{
    int idx = blockIdx.x * 256 + threadIdx.x;
    if (idx >= 4*4*8*4*4*8) return;
    int q = idx & 7; int t = idx >> 3;
    int p = t & 3;  t >>= 2;
    int o = t & 3;  t >>= 2;
    int y = t & 7;  t >>= 3;
    int x = t & 3;  t >>= 2;
    int w = t & 3;

    float c[RANK];
    for (int v = 0; v < RANK; ++v) c[v] = 0.f;
    for (int u = 0; u < RANK; ++u) {
        float a = g1[(w*4 + o)*RANK + u];
        const float* g2p = g2 + ((u*4 + x)*4 + p)*RANK;
        for (int v = 0; v < RANK; ++v) c[v] += a * g2p[v];
    }
    float d[RANK];
    for (int r = 0; r < RANK; ++r) d[r] = 0.f;
    for (int v = 0; v < RANK; ++v) {
        float cv = c[v];
        const float* g3p = g3 + ((v*8 + y)*8 + q)*RANK;
        for (int r = 0; r < RANK; ++r) d[r] += cv * g3p[r];
    }
    for (int z = 0; z < 4; ++z) {
        for (int s = 0; s < 4; ++s) {
            float acc = 0.f;
            for (int r = 0; r < RANK; ++r) acc += d[r] * g4[(r*4 + z)*4 + s];
            int i = ((w*4 + x)*8 + y)*4 + z;
            int j = ((o*4 + p)*8 + q)*4 + s;
            W[i*DM + j] = acc;
        }
    }
}

// ---------------- tiled fp32 GEMM: [8192,512] x [512,512] + bias ----------------
// mode 0: bf16 out[((b*NH+h)*LL + l)*DK + d] * oscale   (projection, head layout)
// mode 1: f32  out[m*DM + n]                            (fc, row-major)
__global__ __launch_bounds__(256) void gemm_kernel(
    const float* __restrict__ X, const float* __restrict__ W,
    const float* __restrict__ bias, float* __restrict__ outF,
    bf16* __restrict__ outB, int mode, float oscale)
{
    __shared__ float As[16][65];
    __shared__ float Bs[16][65];
    int m0 = blockIdx.x * 64;
    int n0 = blockIdx.y * 64;
    int t  = threadIdx.x;
    int tx = t & 15, ty = t >> 4;
    float acc[4][4] = {};

    for (int k0 = 0; k0 < DM; k0 += 16) {
        for (int i = 0; i < 4; ++i) {
            int e = t + i*256;
            int m = e >> 4, k = e & 15;
            As[k][m] = X[(size_t)(m0+m)*DM + k0 + k];
        }
        for (int i = 0; i < 4; ++i) {
            int e = t + i*256;
            int k = e >> 6, n = e & 63;
            Bs[k][n] = W[(size_t)(k0+k)*DM + n0 + n];
        }
        __syncthreads();
        #pragma unroll
        for (int k = 0; k < 16; ++k) {
            float a[4], b[4];
            #pragma unroll
            for (int i = 0; i < 4; ++i) a[i] = As[k][ty*4+i];
            #pragma unroll
            for (int j = 0; j < 4; ++j) b[j] = Bs[k][tx*4+j];
            #pragma unroll
            for (int i = 0; i < 4; ++i)
                #pragma unroll
                for (int j = 0; j < 4; ++j) acc[i][j] += a[i]*b[j];
        }
        __syncthreads();
    }

    for (int i = 0; i < 4; ++i) {
        int m = m0 + ty*4 + i;
        int l = m & (LL-1), b = m >> 11;
        for (int j = 0; j < 4; ++j) {
            int n = n0 + tx*4 + j;
            float val = (acc[i][j] + bias[n]) * oscale;
            if (mode == 0) {
                int h = n >> 6, d = n & 63;
                outB[(((size_t)(b*NH + h))*LL + l)*DK + d] = __float2bfloat16(val);
            } else {
                outF[(size_t)m*DM + n] = val;
            }
        }
    }
}

// ---------------- MFMA attention: 64 q-rows/block, two-pass softmax ----------------
// pass A: online row max/sum over S = Q K^T   (S never stored)
// pass B: recompute S, P = exp(S-m)/l -> write attn (fp32), bf16 P -> LDS, PV via MFMA
__global__ __launch_bounds__(256, 2) void attn_mfma_kernel(
    const bf16* __restrict__ Qh, const bf16* __restrict__ Kh,
    const bf16* __restrict__ Vh, float* __restrict__ attn,
    float* __restrict__ O)
{
    __shared__ __align__(16) bf16 Qs[64][88];       // 11.0 KB  (176B stride: 2-way)
    __shared__ __align__(16) bf16 Ks[128][88];      // 22.0 KB
    __shared__ __align__(16) bf16 Vt[64][136];      // 17.0 KB  V^T: [d][key]
    __shared__ __align__(16) bf16 Ps[4][16][136];   // 17.0 KB  per-wave P tile

    int qt = blockIdx.x, bh = blockIdx.y;
    int q0 = qt * 64;
    int t = threadIdx.x;
    int lane = t & 63, wave = t >> 6;
    int l15 = lane & 15, l4 = lane >> 4;

    const bf16* Qp = Qh + (size_t)bh * LL * DK + (size_t)q0 * DK;
    const bf16* Kp = Kh + (size_t)bh * LL * DK;
    const bf16* Vp = Vh + (size_t)bh * LL * DK;

    // stage Q tile 64x64 (already pre-scaled by 1/sqrt(dk))
    for (int i = t; i < 64*8; i += 256) {
        int row = i >> 3, g = i & 7;
        *(short8*)&Qs[row][g*8] = *(const short8*)&Qp[(size_t)row*DK + g*8];
    }
    __syncthreads();

    int qr0 = wave * 16;
    short8 aq0 = *(const short8*)&Qs[qr0 + l15][l4*8];
    short8 aq1 = *(const short8*)&Qs[qr0 + l15][32 + l4*8];

    float m[4], lsum[4];
    #pragma unroll
    for (int r = 0; r < 4; ++r) { m[r] = -1e30f; lsum[r] = 0.f; }

    // ---------- pass A: stats ----------
    for (int kc = 0; kc < LL; kc += 128) {
        for (int i = t; i < 128*8; i += 256) {
            int row = i >> 3, g = i & 7;
            *(short8*)&Ks[row][g*8] = *(const short8*)&Kp[(size_t)(kc+row)*DK + g*8];
        }
        __syncthreads();

        f32x4 s[8];
        #pragma unroll
        for (int ct = 0; ct < 8; ++ct) {
            f32x4 acc = {0.f, 0.f, 0.f, 0.f};
            short8 b0 = *(const short8*)&Ks[ct*16 + l15][l4*8];
            short8 b1 = *(const short8*)&Ks[ct*16 + l15][32 + l4*8];
            acc = __builtin_amdgcn_mfma_f32_16x16x32_bf16(aq0, b0, acc, 0, 0, 0);
            acc = __builtin_amdgcn_mfma_f32_16x16x32_bf16(aq1, b1, acc, 0, 0, 0);
            s[ct] = acc;
        }
        #pragma unroll
        for (int r = 0; r < 4; ++r) {
            float tm = s[0][r];
            #pragma unroll
            for (int ct = 1; ct < 8; ++ct) tm = fmaxf(tm, s[ct][r]);
            #pragma unroll
            for (int off = 8; off >= 1; off >>= 1) tm = fmaxf(tm, __shfl_xor(tm, off));
            float mn = fmaxf(m[r], tm);
            float sc = __expf(m[r] - mn);
            float ss = 0.f;
            #pragma unroll
            for (int ct = 0; ct < 8; ++ct) ss += __expf(s[ct][r] - mn);
            #pragma unroll
            for (int off = 8; off >= 1; off >>= 1) ss += __shfl_xor(ss, off);
            lsum[r] = lsum[r] * sc + ss;
            m[r] = mn;
        }
        __syncthreads();
    }

    float invl[4];
    #pragma unroll
    for (int r = 0; r < 4; ++r) invl[r] = 1.0f / lsum[r];

    // ---------- pass B: P write + PV ----------
    f32x4 o_acc[4] = {};
    for (int kc = 0; kc < LL; kc += 128) {
        for (int i = t; i < 128*8; i += 256) {
            int row = i >> 3, g = i & 7;
            *(short8*)&Ks[row][g*8] = *(const short8*)&Kp[(size_t)(kc+row)*DK + g*8];
        }
        // V chunk, transposed into Vt[d][key]
        for (int i = t; i < 1024; i += 256) {
            int key = i & 127, dg = i >> 7;
            short8 v = *(const short8*)&Vp[(size_t)(kc+key)*DK + dg*8];
            #pragma unroll
            for (int j = 0; j < 8; ++j) Vt[dg*8 + j][key] = ((bf16*)&v)[j];
        }
        __syncthreads();

        f32x4 s[8];
        #pragma unroll
        for (int ct = 0; ct < 8; ++ct) {
            f32x4 acc = {0.f, 0.f, 0.f, 0.f};
            short8 b0 = *(const short8*)&Ks[ct*16 + l15][l4*8];
            short8 b1 = *(const short8*)&Ks[ct*16 + l15][32 + l4*8];
            acc = __builtin_amdgcn_mfma_f32_16x16x32_bf16(aq0, b0, acc, 0, 0, 0);
            acc = __builtin_amdgcn_mfma_f32_16x16x32_bf16(aq1, b1, acc, 0, 0, 0);
            s[ct] = acc;
        }

        float* ap = attn + ((size_t)bh * LL + q0 + qr0) * LL + kc;
        #pragma unroll
        for (int ct = 0; ct < 8; ++ct) {
            #pragma unroll
            for (int r = 0; r < 4; ++r) {
                int row = l4*4 + r;
                float p = __expf(s[ct][r] - m[r]) * invl[r];
                ap[(size_t)row * LL + ct*16 + l15] = p;
                Ps[wave][row][ct*16 + l15] = __float2bfloat16(p);
            }
        }

        // PV: O[16q][64d] += P[16q][128k] * V[128k][64d]
        #pragma unroll
        for (int kt = 0; kt < 4; ++kt) {
            short8 a = *(const short8*)&Ps[wave][l15][kt*32 + l4*8];
            #pragma unroll
            for (int dt = 0; dt < 4; ++dt) {
                short8 b = *(const short8*)&Vt[dt*16 + l15][kt*32 + l4*8];
                o_acc[dt] = __builtin_amdgcn_mfma_f32_16x16x32_bf16(a, b, o_acc[dt], 0, 0, 0);
            }
        }
        __syncthreads();
    }

    int b = bh >> 3, h = bh & 7;
    #pragma unroll
    for (int dt = 0; dt < 4; ++dt)
        #pragma unroll
        for (int r = 0; r < 4; ++r) {
            int row = q0 + qr0 + l4*4 + r;
            O[((size_t)b * LL + row) * DM + h*DK + dt*16 + l15] = o_acc[dt][r];
        }
}

// ---------------- residual + LayerNorm ----------------
__global__ __launch_bounds__(256) void ln_kernel(
    const float* __restrict__ Y, const float* __restrict__ Res,
    const float* __restrict__ g, const float* __restrict__ bta,
    float* __restrict__ out)
{
    int row = blockIdx.x;
    int t = threadIdx.x;
    const float* yp = Y  + (size_t)row*DM;
    const float* rp = Res + (size_t)row*DM;
    float v0 = yp[t]       + rp[t];
    float v1 = yp[t + 256] + rp[t + 256];
    float s1 = v0 + v1;
    float s2 = v0*v0 + v1*v1;
    __shared__ float red1[4], red2[4];
    #pragma unroll
    for (int off = 32; off >= 1; off >>= 1) {
        s1 += __shfl_xor(s1, off);
        s2 += __shfl_xor(s2, off);
    }
    int w = t >> 6;
    if ((t & 63) == 0) { red1[w] = s1; red2[w] = s2; }
    __syncthreads();
    float mu = (red1[0]+red1[1]+red1[2]+red1[3]) * (1.0f/DM);
    float ms = (red2[0]+red2[1]+red2[2]+red2[3]) * (1.0f/DM);
    float inv = rsqrtf(ms - mu*mu + 1e-12f);
    out[(size_t)row*DM + t]       = (v0 - mu)*inv*g[t]       + bta[t];
    out[(size_t)row*DM + t + 256] = (v1 - mu)*inv*g[t + 256] + bta[t + 256];
}

extern "C" void kernel_launch(void* const* d_in, const int* in_sizes, int n_in,
                              void* d_out, int out_size, void* d_ws, size_t ws_size,
                              hipStream_t stream)
{
    const float* G[4][5];
    for (int s = 0; s < 4; ++s)
        for (int i = 0; i < 5; ++i)
            G[s][i] = (const float*)d_in[s*5 + i];
    const float* q   = (const float*)d_in[20];
    const float* k   = (const float*)d_in[21];
    const float* v   = (const float*)d_in[22];
    const float* lng = (const float*)d_in[23];
    const float* lnb = (const float*)d_in[24];

    float* out  = (float*)d_out;                         // [B,L,DM]
    float* attn = out + (size_t)BB*LL*DM;                // [B,NH,L,L]

    float* ws = (float*)d_ws;
    float* W  = ws;                                      // 4 * 512*512 f32
    bf16* qh  = (bf16*)(W + 4*(size_t)DM*DM);            // [B,NH,L,DK] bf16
    bf16* kh  = qh + (size_t)BB*LL*DM;
    bf16* vh  = kh + (size_t)BB*LL*DM;
    float* o  = (float*)(vh + (size_t)BB*LL*DM);         // [B,L,DM] f32
    float* y  = o + (size_t)BB*LL*DM;                    // [B,L,DM] f32

    for (int s = 0; s < 4; ++s)
        build_w_kernel<<<64, 256, 0, stream>>>(G[s][0], G[s][1], G[s][2], G[s][3],
                                               W + (size_t)s*DM*DM);

    dim3 gg(BB*LL/64, DM/64);
    gemm_kernel<<<gg, 256, 0, stream>>>(q, W + 0*(size_t)DM*DM, G[0][4], nullptr, qh, 0, 0.125f);
    gemm_kernel<<<gg, 256, 0, stream>>>(k, W + 1*(size_t)DM*DM, G[1][4], nullptr, kh, 0, 1.0f);
    gemm_kernel<<<gg, 256, 0, stream>>>(v, W + 2*(size_t)DM*DM, G[2][4], nullptr, vh, 0, 1.0f);

    dim3 ga(LL/64, BB*NH);
    attn_mfma_kernel<<<ga, 256, 0, stream>>>(qh, kh, vh, attn, o);

    gemm_kernel<<<gg, 256, 0, stream>>>(o, W + 3*(size_t)DM*DM, G[3][4], y, nullptr, 1, 1.0f);

    ln_kernel<<<BB*LL, 256, 0, stream>>>(y, q, lng, lnb, out);
}

// Round 3
// 470.787 us; speedup vs baseline: 20.7746x; 1.5684x over previous
//
#include <hip/hip_runtime.h>
#include <hip/hip_bf16.h>
#include <math.h>

#define BB 4
#define LL 2048
#define DM 512
#define NH 8
#define DK 64
#define RANK 20

typedef __attribute__((ext_vector_type(8))) short short8;
typedef __attribute__((ext_vector_type(4))) short short4b;
typedef __attribute__((ext_vector_type(4))) float f32x4;
typedef __hip_bfloat16 bf16;

__device__ inline short to_bf(float x) {
    bf16 h = __float2bfloat16(x);
    return *reinterpret_cast<short*>(&h);
}

// ---------------- build W^T (bf16) from TT cores ----------------
// W[i][j]; we store Wt[j][i] in bf16 (B-operand wants out-dim-major, k-contiguous)
__global__ __launch_bounds__(256) void build_w_kernel(
    const float* __restrict__ g1, const float* __restrict__ g2,
    const float* __restrict__ g3, const float* __restrict__ g4,
    bf16* __restrict__ Wt)
{
    int idx = blockIdx.x * 256 + threadIdx.x;
    if (idx >= 4*4*8*4*4*8) return;
    int q = idx & 7; int t = idx >> 3;
    int p = t & 3;  t >>= 2;
    int o = t & 3;  t >>= 2;
    int y = t & 7;  t >>= 3;
    int x = t & 3;  t >>= 2;
    int w = t & 3;

    float c[RANK];
    for (int v = 0; v < RANK; ++v) c[v] = 0.f;
    for (int u = 0; u < RANK; ++u) {
        float a = g1[(w*4 + o)*RANK + u];
        const float* g2p = g2 + ((u*4 + x)*4 + p)*RANK;
        for (int v = 0; v < RANK; ++v) c[v] += a * g2p[v];
    }
    float d[RANK];
    for (int r = 0; r < RANK; ++r) d[r] = 0.f;
    for (int v = 0; v < RANK; ++v) {
        float cv = c[v];
        const float* g3p = g3 + ((v*8 + y)*8 + q)*RANK;
        for (int r = 0; r < RANK; ++r) d[r] += cv * g3p[r];
    }
    for (int z = 0; z < 4; ++z) {
        for (int s = 0; s < 4; ++s) {
            float acc = 0.f;
            for (int r = 0; r < RANK; ++r) acc += d[r] * g4[(r*4 + z)*4 + s];
            int i = ((w*4 + x)*8 + y)*4 + z;
            int j = ((o*4 + p)*8 + q)*4 + s;
            Wt[(size_t)j*DM + i] = __float2bfloat16(acc);
        }
    }
}

// ---------------- MFMA GEMM: [8192,512](f32->bf16) x Wt[512,512](bf16) + bias ----------------
// mode 0: bf16 out[((b*NH+h)*LL + l)*DK + d] * oscale   (projection, head layout)
// mode 1: f32  out[m*DM + n]                            (fc, row-major)
#define GS 68   // LDS k-stride (bf16 elems): 136B -> uniform bank spread
__global__ __launch_bounds__(256) void gemm_mfma_kernel(
    const float* __restrict__ X, const bf16* __restrict__ Wt,
    const float* __restrict__ bias, float* __restrict__ outF,
    bf16* __restrict__ outB, int mode, float oscale)
{
    __shared__ __align__(16) bf16 Xs[128][GS];
    __shared__ __align__(16) bf16 Ws[128][GS];

    int m0 = blockIdx.x * 128;
    int n0 = blockIdx.y * 128;
    int t  = threadIdx.x;
    int lane = t & 63, wave = t >> 6;
    int l15 = lane & 15, l4 = lane >> 4;
    int wm = wave >> 1, wn = wave & 1;

    f32x4 acc[4][4] = {};

    for (int k0 = 0; k0 < DM; k0 += 64) {
        // stage A: 128x64 fp32 -> bf16
        {
            int row = t >> 4, f4 = t & 15;
            #pragma unroll
            for (int i = 0; i < 8; ++i) {
                int r = row + i*16;
                float4 xv = *(const float4*)&X[(size_t)(m0 + r)*DM + k0 + f4*4];
                short4b h;
                h.x = to_bf(xv.x); h.y = to_bf(xv.y);
                h.z = to_bf(xv.z); h.w = to_bf(xv.w);
                *(short4b*)&Xs[r][f4*4] = h;
            }
        }
        // stage B: 128x64 bf16
        {
            #pragma unroll
            for (int i = 0; i < 4; ++i) {
                int e = i*256 + t;
                int r = e >> 3, seg = e & 7;
                short8 wv = *(const short8*)&Wt[(size_t)(n0 + r)*DM + k0 + seg*8];
                *(short8*)&Ws[r][seg*8] = wv;
            }
        }
        __syncthreads();

        #pragma unroll
        for (int kh = 0; kh < 2; ++kh) {
            short8 a[4], b[4];
            #pragma unroll
            for (int mt = 0; mt < 4; ++mt)
                a[mt] = *(const short8*)&Xs[wm*64 + mt*16 + l15][kh*32 + l4*8];
            #pragma unroll
            for (int nt = 0; nt < 4; ++nt)
                b[nt] = *(const short8*)&Ws[wn*64 + nt*16 + l15][kh*32 + l4*8];
            #pragma unroll
            for (int mt = 0; mt < 4; ++mt)
                #pragma unroll
                for (int nt = 0; nt < 4; ++nt)
                    acc[mt][nt] = __builtin_amdgcn_mfma_f32_16x16x32_bf16(
                        a[mt], b[nt], acc[mt][nt], 0, 0, 0);
        }
        __syncthreads();
    }

    // epilogue
    #pragma unroll
    for (int mt = 0; mt < 4; ++mt) {
        #pragma unroll
        for (int r = 0; r < 4; ++r) {
            int m = m0 + wm*64 + mt*16 + l4*4 + r;
            int l = m & (LL-1), bb = m >> 11;
            #pragma unroll
            for (int nt = 0; nt < 4; ++nt) {
                int n = n0 + wn*64 + nt*16 + l15;
                float val = (acc[mt][nt][r] + bias[n]) * oscale;
                if (mode == 0) {
                    int h = n >> 6, d = n & 63;
                    outB[(((size_t)(bb*NH + h))*LL + l)*DK + d] = __float2bfloat16(val);
                } else {
                    outF[(size_t)m*DM + n] = val;
                }
            }
        }
    }
}

// ---------------- MFMA attention: 64 q-rows/block, two-pass softmax ----------------
__global__ __launch_bounds__(256, 2) void attn_mfma_kernel(
    const bf16* __restrict__ Qh, const bf16* __restrict__ Kh,
    const bf16* __restrict__ Vh, float* __restrict__ attn,
    float* __restrict__ O)
{
    __shared__ __align__(16) bf16 Qs[64][88];
    __shared__ __align__(16) bf16 Ks[128][88];
    __shared__ __align__(16) bf16 Vt[64][136];
    __shared__ __align__(16) bf16 Ps[4][16][136];

    int qt = blockIdx.x, bh = blockIdx.y;
    int q0 = qt * 64;
    int t = threadIdx.x;
    int lane = t & 63, wave = t >> 6;
    int l15 = lane & 15, l4 = lane >> 4;

    const bf16* Qp = Qh + (size_t)bh * LL * DK + (size_t)q0 * DK;
    const bf16* Kp = Kh + (size_t)bh * LL * DK;
    const bf16* Vp = Vh + (size_t)bh * LL * DK;

    for (int i = t; i < 64*8; i += 256) {
        int row = i >> 3, g = i & 7;
        *(short8*)&Qs[row][g*8] = *(const short8*)&Qp[(size_t)row*DK + g*8];
    }
    __syncthreads();

    int qr0 = wave * 16;
    short8 aq0 = *(const short8*)&Qs[qr0 + l15][l4*8];
    short8 aq1 = *(const short8*)&Qs[qr0 + l15][32 + l4*8];

    float m[4], lsum[4];
    #pragma unroll
    for (int r = 0; r < 4; ++r) { m[r] = -1e30f; lsum[r] = 0.f; }

    // ---------- pass A: stats ----------
    for (int kc = 0; kc < LL; kc += 128) {
        for (int i = t; i < 128*8; i += 256) {
            int row = i >> 3, g = i & 7;
            *(short8*)&Ks[row][g*8] = *(const short8*)&Kp[(size_t)(kc+row)*DK + g*8];
        }
        __syncthreads();

        f32x4 s[8];
        #pragma unroll
        for (int ct = 0; ct < 8; ++ct) {
            f32x4 acc = {0.f, 0.f, 0.f, 0.f};
            short8 b0 = *(const short8*)&Ks[ct*16 + l15][l4*8];
            short8 b1 = *(const short8*)&Ks[ct*16 + l15][32 + l4*8];
            acc = __builtin_amdgcn_mfma_f32_16x16x32_bf16(aq0, b0, acc, 0, 0, 0);
            acc = __builtin_amdgcn_mfma_f32_16x16x32_bf16(aq1, b1, acc, 0, 0, 0);
            s[ct] = acc;
        }
        #pragma unroll
        for (int r = 0; r < 4; ++r) {
            float tm = s[0][r];
            #pragma unroll
            for (int ct = 1; ct < 8; ++ct) tm = fmaxf(tm, s[ct][r]);
            #pragma unroll
            for (int off = 8; off >= 1; off >>= 1) tm = fmaxf(tm, __shfl_xor(tm, off));
            float mn = fmaxf(m[r], tm);
            float sc = __expf(m[r] - mn);
            float ss = 0.f;
            #pragma unroll
            for (int ct = 0; ct < 8; ++ct) ss += __expf(s[ct][r] - mn);
            #pragma unroll
            for (int off = 8; off >= 1; off >>= 1) ss += __shfl_xor(ss, off);
            lsum[r] = lsum[r] * sc + ss;
            m[r] = mn;
        }
        __syncthreads();
    }

    float invl[4];
    #pragma unroll
    for (int r = 0; r < 4; ++r) invl[r] = 1.0f / lsum[r];

    // ---------- pass B: P write + PV ----------
    f32x4 o_acc[4] = {};
    for (int kc = 0; kc < LL; kc += 128) {
        for (int i = t; i < 128*8; i += 256) {
            int row = i >> 3, g = i & 7;
            *(short8*)&Ks[row][g*8] = *(const short8*)&Kp[(size_t)(kc+row)*DK + g*8];
        }
        for (int i = t; i < 1024; i += 256) {
            int key = i & 127, dg = i >> 7;
            short8 v = *(const short8*)&Vp[(size_t)(kc+key)*DK + dg*8];
            #pragma unroll
            for (int j = 0; j < 8; ++j) Vt[dg*8 + j][key] = ((bf16*)&v)[j];
        }
        __syncthreads();

        f32x4 s[8];
        #pragma unroll
        for (int ct = 0; ct < 8; ++ct) {
            f32x4 acc = {0.f, 0.f, 0.f, 0.f};
            short8 b0 = *(const short8*)&Ks[ct*16 + l15][l4*8];
            short8 b1 = *(const short8*)&Ks[ct*16 + l15][32 + l4*8];
            acc = __builtin_amdgcn_mfma_f32_16x16x32_bf16(aq0, b0, acc, 0, 0, 0);
            acc = __builtin_amdgcn_mfma_f32_16x16x32_bf16(aq1, b1, acc, 0, 0, 0);
            s[ct] = acc;
        }

        float* ap = attn + ((size_t)bh * LL + q0 + qr0) * LL + kc;
        #pragma unroll
        for (int ct = 0; ct < 8; ++ct) {
            #pragma unroll
            for (int r = 0; r < 4; ++r) {
                int row = l4*4 + r;
                float p = __expf(s[ct][r] - m[r]) * invl[r];
                ap[(size_t)row * LL + ct*16 + l15] = p;
                Ps[wave][row][ct*16 + l15] = __float2bfloat16(p);
            }
        }

        #pragma unroll
        for (int kt = 0; kt < 4; ++kt) {
            short8 a = *(const short8*)&Ps[wave][l15][kt*32 + l4*8];
            #pragma unroll
            for (int dt = 0; dt < 4; ++dt) {
                short8 b = *(const short8*)&Vt[dt*16 + l15][kt*32 + l4*8];
                o_acc[dt] = __builtin_amdgcn_mfma_f32_16x16x32_bf16(a, b, o_acc[dt], 0, 0, 0);
            }
        }
        __syncthreads();
    }

    int b = bh >> 3, h = bh & 7;
    #pragma unroll
    for (int dt = 0; dt < 4; ++dt)
        #pragma unroll
        for (int r = 0; r < 4; ++r) {
            int row = q0 + qr0 + l4*4 + r;
            O[((size_t)b * LL + row) * DM + h*DK + dt*16 + l15] = o_acc[dt][r];
        }
}

// ---------------- residual + LayerNorm ----------------
__global__ __launch_bounds__(256) void ln_kernel(
    const float* __restrict__ Y, const float* __restrict__ Res,
    const float* __restrict__ g, const float* __restrict__ bta,
    float* __restrict__ out)
{
    int row = blockIdx.x;
    int t = threadIdx.x;
    const float* yp = Y  + (size_t)row*DM;
    const float* rp = Res + (size_t)row*DM;
    float v0 = yp[t]       + rp[t];
    float v1 = yp[t + 256] + rp[t + 256];
    float s1 = v0 + v1;
    float s2 = v0*v0 + v1*v1;
    __shared__ float red1[4], red2[4];
    #pragma unroll
    for (int off = 32; off >= 1; off >>= 1) {
        s1 += __shfl_xor(s1, off);
        s2 += __shfl_xor(s2, off);
    }
    int w = t >> 6;
    if ((t & 63) == 0) { red1[w] = s1; red2[w] = s2; }
    __syncthreads();
    float mu = (red1[0]+red1[1]+red1[2]+red1[3]) * (1.0f/DM);
    float ms = (red2[0]+red2[1]+red2[2]+red2[3]) * (1.0f/DM);
    float inv = rsqrtf(ms - mu*mu + 1e-12f);
    out[(size_t)row*DM + t]       = (v0 - mu)*inv*g[t]       + bta[t];
    out[(size_t)row*DM + t + 256] = (v1 - mu)*inv*g[t + 256] + bta[t + 256];
}

extern "C" void kernel_launch(void* const* d_in, const int* in_sizes, int n_in,
                              void* d_out, int out_size, void* d_ws, size_t ws_size,
                              hipStream_t stream)
{
    const float* G[4][5];
    for (int s = 0; s < 4; ++s)
        for (int i = 0; i < 5; ++i)
            G[s][i] = (const float*)d_in[s*5 + i];
    const float* q   = (const float*)d_in[20];
    const float* k   = (const float*)d_in[21];
    const float* v   = (const float*)d_in[22];
    const float* lng = (const float*)d_in[23];
    const float* lnb = (const float*)d_in[24];

    float* out  = (float*)d_out;                         // [B,L,DM]
    float* attn = out + (size_t)BB*LL*DM;                // [B,NH,L,L]

    bf16* wt = (bf16*)d_ws;                              // 4 * 512*512 bf16 (W^T)
    bf16* qh = wt + 4*(size_t)DM*DM;                     // [B,NH,L,DK] bf16
    bf16* kh = qh + (size_t)BB*LL*DM;
    bf16* vh = kh + (size_t)BB*LL*DM;
    float* o  = (float*)(vh + (size_t)BB*LL*DM);         // [B,L,DM] f32
    float* y  = o + (size_t)BB*LL*DM;                    // [B,L,DM] f32

    for (int s = 0; s < 4; ++s)
        build_w_kernel<<<64, 256, 0, stream>>>(G[s][0], G[s][1], G[s][2], G[s][3],
                                               wt + (size_t)s*DM*DM);

    dim3 gg(BB*LL/128, DM/128);
    gemm_mfma_kernel<<<gg, 256, 0, stream>>>(q, wt + 0*(size_t)DM*DM, G[0][4], nullptr, qh, 0, 0.125f);
    gemm_mfma_kernel<<<gg, 256, 0, stream>>>(k, wt + 1*(size_t)DM*DM, G[1][4], nullptr, kh, 0, 1.0f);
    gemm_mfma_kernel<<<gg, 256, 0, stream>>>(v, wt + 2*(size_t)DM*DM, G[2][4], nullptr, vh, 0, 1.0f);

    dim3 ga(LL/64, BB*NH);
    attn_mfma_kernel<<<ga, 256, 0, stream>>>(qh, kh, vh, attn, o);

    gemm_mfma_kernel<<<gg, 256, 0, stream>>>(o, wt + 3*(size_t)DM*DM, G[3][4], y, nullptr, 1, 1.0f);

    ln_kernel<<<BB*LL, 256, 0, stream>>>(y, q, lng, lnb, out);
}